// Round 2
// baseline (117.387 us; speedup 1.0000x reference)
//
#include <hip/hip_runtime.h>

#define D_K 576
#define LBDA_INV 2.0f    // 1/lbda, lbda=0.5
#define HALF_LBDA 0.5f
#define EPS 0.01f
#define DSTRIDE 136      // 128 + 8 bf16 pad (DP scratch only; MFMA tiles unpadded)

#define NQROW 16384      // 2048*8 query frame rows
#define NSROW 512        // 64*8 support frame rows

typedef __attribute__((ext_vector_type(8))) short short8;
typedef __attribute__((ext_vector_type(4))) short short4v;
typedef __attribute__((ext_vector_type(4))) float f32x4;

__device__ inline short f2bf(float f) {
    unsigned u = __float_as_uint(f);
    u += 0x7FFF + ((u >> 16) & 1);   // round-to-nearest-even
    return (short)(u >> 16);
}
__device__ inline float bf2f(unsigned short s) {
    return __uint_as_float(((unsigned)s) << 16);
}

// async 16B global->LDS: lds dst must be wave-uniform base (+lane*16 implicit)
__device__ inline void load_lds16(const void* g, void* l) {
    __builtin_amdgcn_global_load_lds(
        (const __attribute__((address_space(1))) unsigned int*)g,
        (__attribute__((address_space(3))) unsigned int*)l,
        16, 0, 0);
}

// ---------------- prep: norms + f32->bf16 conversion, one wave per row ----------------
__global__ __launch_bounds__(256) void prep_kernel(
        const float* __restrict__ sup, const float* __restrict__ qry,
        unsigned short* __restrict__ qb, unsigned short* __restrict__ sb,
        float* __restrict__ qn, float* __restrict__ sn) {
    int t = threadIdx.x;
    int row = blockIdx.x * 4 + (t >> 6);
    int lane = t & 63;
    bool isq = row < NQROW;
    const float* base = isq ? (qry + (size_t)row * D_K)
                            : (sup + (size_t)(row - NQROW) * D_K);
    unsigned short* dst = isq ? (qb + (size_t)row * D_K)
                              : (sb + (size_t)(row - NQROW) * D_K);
    float s = 0.f;
    // 576 floats = 144 float4 chunks; lanes cover 64+64+16
    for (int c = lane; c < 144; c += 64) {
        float4 v = *(const float4*)(base + c * 4);
        s += v.x * v.x + v.y * v.y + v.z * v.z + v.w * v.w;
        short4v o = {f2bf(v.x), f2bf(v.y), f2bf(v.z), f2bf(v.w)};
        *(short4v*)(dst + c * 4) = o;
    }
#pragma unroll
    for (int off = 32; off > 0; off >>= 1)
        s += __shfl_down(s, off);
    if (lane == 0) {
        float r = sqrtf(s);
        if (isq) qn[row] = r;
        else sn[row - NQROW] = r;
    }
}

// ---------------- soft-min helpers (lbda = 0.5) ----------------
__device__ inline float softmin3(float a, float b, float c) {
    float mn = fminf(a, fminf(b, c));
    float s = __expf(-LBDA_INV * (a - mn)) + __expf(-LBDA_INV * (b - mn)) +
              __expf(-LBDA_INV * (c - mn));
    return mn - HALF_LBDA * __logf(s);
}
__device__ inline float softmin2(float a, float b) {
    float mn = fminf(a, b);
    float s = __expf(-LBDA_INV * (a - mn)) + __expf(-LBDA_INV * (b - mn));
    return mn - HALF_LBDA * __logf(s);
}

// OTAM DP over an 8x8 dist tile; element (l,s) at d[l*RS + s*CS].
template <int RS, int CS>
__device__ float otam_dp(const float* d) {
    float prev[10], cur[10];
    prev[0] = 0.f;
#pragma unroll
    for (int m = 1; m <= 8; ++m) prev[m] = prev[m - 1] + d[0 * RS + (m - 1) * CS];
    prev[9] = prev[8];  // pad col, d=0
#pragma unroll
    for (int l = 1; l < 8; ++l) {
        cur[0] = 0.f;
        cur[1] = d[l * RS + 0 * CS] + softmin3(prev[0], 0.f, prev[1]);
#pragma unroll
        for (int m = 2; m <= 8; ++m)
            cur[m] = d[l * RS + (m - 1) * CS] + softmin2(prev[m - 1], cur[m - 1]);
        cur[9] = softmin3(prev[8], cur[8], prev[9]);
#pragma unroll
        for (int m = 0; m < 10; ++m) prev[m] = cur[m];
    }
    return prev[9];
}

// ---------------- fused: 128x128 frame-dist tile (MFMA, async staging) + 256 DPs ----------
__global__ __launch_bounds__(256, 2) void fused_kernel(
        const unsigned short* __restrict__ qb, const unsigned short* __restrict__ sb,
        const float* __restrict__ qn, const float* __restrict__ sn,
        float* __restrict__ out) {
    // chunk-major MFMA tiles: chunk p = c*128+r holds X[r][k0+c*8 .. +7], at offset p*16B
    __shared__ unsigned short As[512 * 8];   // 8 KB
    __shared__ unsigned short Bs[512 * 8];   // 8 KB
    __shared__ unsigned short Ds[128 * DSTRIDE];  // 34.8 KB

    const int t = threadIdx.x;
    // XCD swizzle: each XCD (b&7) owns qblks [16x..16x+15] x all 4 sblks ->
    // per-XCD L2 working set ~3MB (16 q-tiles bf16 + all of sb)
    const int b = blockIdx.x;
    const int xcd = b & 7, s = b >> 3;
    const int sblk = s >> 4;                 // 0..3
    const int qblk = xcd * 16 + (s & 15);    // 0..127

    const unsigned short* Ag = qb + (size_t)qblk * 128 * D_K;
    const unsigned short* Bg = sb + (size_t)sblk * 128 * D_K;

    const int lane = t & 63;
    const int wave = t >> 6;
    const int wm = wave >> 1, wn = wave & 1;
    const int col16 = lane & 15, quad = lane >> 4;

    f32x4 acc[4][4];
#pragma unroll
    for (int i = 0; i < 4; ++i)
#pragma unroll
        for (int j = 0; j < 4; ++j) acc[i][j] = (f32x4){0.f, 0.f, 0.f, 0.f};

    for (int k0 = 0; k0 < D_K; k0 += 32) {
        // stage 128x32 bf16 of A and B: 512 chunks each, 2 per thread
#pragma unroll
        for (int i = 0; i < 2; ++i) {
            int p = wave * 64 + i * 256 + lane;     // lane-contiguous chunk id
            int r = p & 127, c = p >> 7;
            load_lds16(Ag + (size_t)r * D_K + k0 + c * 8, &As[(wave * 64 + i * 256) * 8]);
            load_lds16(Bg + (size_t)r * D_K + k0 + c * 8, &Bs[(wave * 64 + i * 256) * 8]);
        }
        __syncthreads();   // drains vmcnt -> LDS tiles ready

        short8 af[4], bf[4];
#pragma unroll
        for (int mt = 0; mt < 4; ++mt) {
            int row = wm * 64 + mt * 16 + col16;
            af[mt] = *(const short8*)(&As[(quad * 128 + row) * 8]);
        }
#pragma unroll
        for (int nt = 0; nt < 4; ++nt) {
            int row = wn * 64 + nt * 16 + col16;
            bf[nt] = *(const short8*)(&Bs[(quad * 128 + row) * 8]);
        }
#pragma unroll
        for (int mt = 0; mt < 4; ++mt)
#pragma unroll
            for (int nt = 0; nt < 4; ++nt)
                acc[mt][nt] = __builtin_amdgcn_mfma_f32_16x16x32_bf16(
                    af[mt], bf[nt], acc[mt][nt], 0, 0, 0);
        __syncthreads();   // everyone done reading before next overwrite
    }

    // epilogue: num -> dist = 1 - num/(|q||s|+eps), park in LDS (bf16)
    // C/D layout: col = lane&15, row = quad*4 + reg
#pragma unroll
    for (int mt = 0; mt < 4; ++mt) {
#pragma unroll
        for (int reg = 0; reg < 4; ++reg) {
            int m = wm * 64 + mt * 16 + quad * 4 + reg;
            float qv = qn[qblk * 128 + m];
#pragma unroll
            for (int nt = 0; nt < 4; ++nt) {
                int n = wn * 64 + nt * 16 + col16;
                float sv = sn[sblk * 128 + n];
                float dist = 1.f - acc[mt][nt][reg] / (qv * sv + EPS);
                Ds[m * DSTRIDE + n] = (unsigned short)f2bf(dist);
            }
        }
    }
    __syncthreads();

    // DP phase: thread t owns pair (ql, sl); 8x8 tile of dists to registers
    const int ql = t >> 4, sl = t & 15;
    float d[64];
#pragma unroll
    for (int l = 0; l < 8; ++l) {
        short8 rowv = *(const short8*)(&Ds[(ql * 8 + l) * DSTRIDE + sl * 8]);
#pragma unroll
        for (int j = 0; j < 8; ++j) d[l * 8 + j] = bf2f((unsigned short)rowv[j]);
    }
    float r1 = otam_dp<8, 1>(d);   // dists
    float r2 = otam_dp<1, 8>(d);   // dists^T
    int qg = qblk * 16 + ql, sg = sblk * 16 + sl;
    out[qg * 64 + sg] = -(r1 + r2);
}

extern "C" void kernel_launch(void* const* d_in, const int* in_sizes, int n_in,
                              void* d_out, int out_size, void* d_ws, size_t ws_size,
                              hipStream_t stream) {
    const float* sup = (const float*)d_in[0];   // [64, 8, 576]
    const float* qry = (const float*)d_in[1];   // [2048, 8, 576]
    float* out = (float*)d_out;                 // [2048, 64]

    // ws layout: qb bf16[16384*576] | sb bf16[512*576] | qn f32[16384] | sn f32[512]
    unsigned short* qb = (unsigned short*)d_ws;
    unsigned short* sb = qb + (size_t)NQROW * D_K;
    float* qn = (float*)(sb + (size_t)NSROW * D_K);
    float* sn = qn + NQROW;

    prep_kernel<<<dim3((NQROW + NSROW) / 4), dim3(256), 0, stream>>>(
        sup, qry, qb, sb, qn, sn);
    fused_kernel<<<dim3(512), dim3(256), 0, stream>>>(qb, sb, qn, sn, out);
}

// Round 3
// 110.670 us; speedup vs baseline: 1.0607x; 1.0607x over previous
//
#include <hip/hip_runtime.h>

#define D_K 576
#define NSLAB 18         // 576 / 32
#define LBDA_INV 2.0f    // 1/lbda, lbda=0.5
#define HALF_LBDA 0.5f
#define EPS 0.01f
#define DSTRIDE 136      // 128 + 8 bf16 pad (DP scratch)

#define NQROW 16384
#define NSROW 512
#define NQT 128          // query tiles of 128 rows
#define NST 4            // support tiles
#define NT 132
#define TILE_ELEMS (128 * D_K)    // ushorts per tile
#define SLAB_ELEMS (128 * 32)     // ushorts per slab (4096)

typedef __attribute__((ext_vector_type(8))) short short8;
typedef __attribute__((ext_vector_type(4))) short short4v;
typedef __attribute__((ext_vector_type(4))) float f32x4;

__device__ inline short f2bf(float f) {
    unsigned u = __float_as_uint(f);
    u += 0x7FFF + ((u >> 16) & 1);   // round-to-nearest-even
    return (short)(u >> 16);
}
__device__ inline float bf2f(unsigned short s) {
    return __uint_as_float(((unsigned)s) << 16);
}

// ---------------- prep: f32 -> bf16 chunk-major tiles + per-slab norm partials ----------
// Tiled image: tile t, slab s, chunk p = c*128 + r (c=k-octet 0..3, r=row 0..127),
// chunk holds X[r][s*32 + c*8 .. +7], 16B, stored contiguously by p.
__global__ __launch_bounds__(256) void prep_kernel(
        const float* __restrict__ sup, const float* __restrict__ qry,
        unsigned short* __restrict__ tb, float* __restrict__ psum) {
    __shared__ unsigned short Ls[SLAB_ELEMS];   // 8 KB, chunk-major
    const int t = threadIdx.x;
    const int slab = blockIdx.x;    // 0..17
    const int tile = blockIdx.y;    // 0..131
    const bool isq = tile < NQT;
    const float* src = (isq ? qry + (size_t)tile * 128 * D_K
                            : sup + (size_t)(tile - NQT) * 128 * D_K) + slab * 32;
    float* ps = psum + ((size_t)tile * NSLAB + slab) * 128;

#pragma unroll
    for (int i = 0; i < 4; ++i) {
        int idx = i * 256 + t;          // 0..1023 float4-chunks of the 128x32 slab
        int r = idx >> 3, c = idx & 7;  // 8 float4 per row; consecutive t -> contiguous
        float4 v = *(const float4*)(src + (size_t)r * D_K + c * 4);
        float ss = v.x * v.x + v.y * v.y + v.z * v.z + v.w * v.w;
        // 8 consecutive lanes cover one row's 32 cols -> reduce within the octet
        ss += __shfl_down(ss, 4);
        ss += __shfl_down(ss, 2);
        ss += __shfl_down(ss, 1);
        if ((t & 7) == 0) ps[r] = ss;   // partial sum-of-squares for this 32-col slab
        int c_in = c >> 1, half = c & 1;
        short4v o = {f2bf(v.x), f2bf(v.y), f2bf(v.z), f2bf(v.w)};
        *(short4v*)(&Ls[(c_in * 128 + r) * 8 + half * 4]) = o;
    }
    __syncthreads();
    // contiguous 8 KB write-out: thread t owns ushorts [t*16, t*16+16)
    unsigned short* dst = tb + (size_t)tile * TILE_ELEMS + (size_t)slab * SLAB_ELEMS;
    *(short8*)(dst + t * 16) = *(const short8*)(&Ls[t * 16]);
    *(short8*)(dst + t * 16 + 8) = *(const short8*)(&Ls[t * 16 + 8]);
}

// ---------------- soft-min helpers (lbda = 0.5) ----------------
__device__ inline float softmin3(float a, float b, float c) {
    float mn = fminf(a, fminf(b, c));
    float s = __expf(-LBDA_INV * (a - mn)) + __expf(-LBDA_INV * (b - mn)) +
              __expf(-LBDA_INV * (c - mn));
    return mn - HALF_LBDA * __logf(s);
}
__device__ inline float softmin2(float a, float b) {
    float mn = fminf(a, b);
    float s = __expf(-LBDA_INV * (a - mn)) + __expf(-LBDA_INV * (b - mn));
    return mn - HALF_LBDA * __logf(s);
}

// OTAM DP over an 8x8 dist tile; element (l,s) at d[l*RS + s*CS].
template <int RS, int CS>
__device__ float otam_dp(const float* d) {
    float prev[10], cur[10];
    prev[0] = 0.f;
#pragma unroll
    for (int m = 1; m <= 8; ++m) prev[m] = prev[m - 1] + d[0 * RS + (m - 1) * CS];
    prev[9] = prev[8];  // pad col, d=0
#pragma unroll
    for (int l = 1; l < 8; ++l) {
        cur[0] = 0.f;
        cur[1] = d[l * RS + 0 * CS] + softmin3(prev[0], 0.f, prev[1]);
#pragma unroll
        for (int m = 2; m <= 8; ++m)
            cur[m] = d[l * RS + (m - 1) * CS] + softmin2(prev[m - 1], cur[m - 1]);
        cur[9] = softmin3(prev[8], cur[8], prev[9]);
#pragma unroll
        for (int m = 0; m < 10; ++m) prev[m] = cur[m];
    }
    return prev[9];
}

// ---------------- fused: barrier-free K-loop (direct coalesced fragment loads) + DP ------
__global__ __launch_bounds__(256, 2) void fused_kernel(
        const unsigned short* __restrict__ tb, const float* __restrict__ psum,
        float* __restrict__ out) {
    __shared__ unsigned short Ds[128 * DSTRIDE];  // 34.8 KB
    __shared__ float qn_l[128], sn_l[128];

    const int t = threadIdx.x;
    // XCD swizzle: blocks sharing a qblk (4 sblks) land on the same XCD -> A reuse in L2
    const int b = blockIdx.x;
    const int xcd = b & 7, s2 = b >> 3;
    const int sblk = s2 >> 4;                 // 0..3
    const int qblk = xcd * 16 + (s2 & 15);    // 0..127

    // norms from per-slab partials (deterministic, no atomics)
    {
        const float* pq = psum + (size_t)qblk * NSLAB * 128;
        const float* ps = psum + (size_t)(NQT + sblk) * NSLAB * 128;
        if (t < 128) {
            float a = 0.f;
#pragma unroll
            for (int sl = 0; sl < NSLAB; ++sl) a += pq[sl * 128 + t];
            qn_l[t] = sqrtf(a);
        } else {
            int r = t - 128;
            float a = 0.f;
#pragma unroll
            for (int sl = 0; sl < NSLAB; ++sl) a += ps[sl * 128 + r];
            sn_l[r] = sqrtf(a);
        }
    }

    const unsigned short* At = tb + (size_t)qblk * TILE_ELEMS;
    const unsigned short* Bt = tb + (size_t)(NQT + sblk) * TILE_ELEMS;

    const int lane = t & 63;
    const int wave = t >> 6;
    const int wm = wave >> 1, wn = wave & 1;
    const int col16 = lane & 15, quad = lane >> 4;

    f32x4 acc[4][4];
#pragma unroll
    for (int i = 0; i < 4; ++i)
#pragma unroll
        for (int j = 0; j < 4; ++j) acc[i][j] = (f32x4){0.f, 0.f, 0.f, 0.f};

    // per-lane fragment offsets within a slab (ushorts); 16 lanes of a quad are contiguous
    int aoff[4], boff[4];
#pragma unroll
    for (int mt = 0; mt < 4; ++mt)
        aoff[mt] = (quad * 128 + wm * 64 + mt * 16 + col16) * 8;
#pragma unroll
    for (int nt = 0; nt < 4; ++nt)
        boff[nt] = (quad * 128 + wn * 64 + nt * 16 + col16) * 8;

#pragma unroll 3
    for (int sl = 0; sl < NSLAB; ++sl) {
        const unsigned short* Asl = At + sl * SLAB_ELEMS;
        const unsigned short* Bsl = Bt + sl * SLAB_ELEMS;
        short8 af[4], bf[4];
#pragma unroll
        for (int mt = 0; mt < 4; ++mt) af[mt] = *(const short8*)(Asl + aoff[mt]);
#pragma unroll
        for (int nt = 0; nt < 4; ++nt) bf[nt] = *(const short8*)(Bsl + boff[nt]);
#pragma unroll
        for (int mt = 0; mt < 4; ++mt)
#pragma unroll
            for (int nt = 0; nt < 4; ++nt)
                acc[mt][nt] = __builtin_amdgcn_mfma_f32_16x16x32_bf16(
                    af[mt], bf[nt], acc[mt][nt], 0, 0, 0);
    }
    __syncthreads();   // qn_l/sn_l visible; everyone past K-loop before Ds writes

    // epilogue: dist = 1 - num/(|q||s|+eps) -> Ds (bf16)
    // C/D layout: col = lane&15, row = quad*4 + reg
#pragma unroll
    for (int mt = 0; mt < 4; ++mt) {
#pragma unroll
        for (int reg = 0; reg < 4; ++reg) {
            int m = wm * 64 + mt * 16 + quad * 4 + reg;
            float qv = qn_l[m];
#pragma unroll
            for (int nt = 0; nt < 4; ++nt) {
                int n = wn * 64 + nt * 16 + col16;
                float sv = sn_l[n];
                float dist = 1.f - acc[mt][nt][reg] / (qv * sv + EPS);
                Ds[m * DSTRIDE + n] = (unsigned short)f2bf(dist);
            }
        }
    }
    __syncthreads();

    // DP phase: thread t owns pair (ql, sl)
    const int ql = t >> 4, sl = t & 15;
    float d[64];
#pragma unroll
    for (int l = 0; l < 8; ++l) {
        short8 rowv = *(const short8*)(&Ds[(ql * 8 + l) * DSTRIDE + sl * 8]);
#pragma unroll
        for (int j = 0; j < 8; ++j) d[l * 8 + j] = bf2f((unsigned short)rowv[j]);
    }
    float r1 = otam_dp<8, 1>(d);   // dists
    float r2 = otam_dp<1, 8>(d);   // dists^T
    int qg = qblk * 16 + ql, sg = sblk * 16 + sl;
    out[qg * 64 + sg] = -(r1 + r2);
}

extern "C" void kernel_launch(void* const* d_in, const int* in_sizes, int n_in,
                              void* d_out, int out_size, void* d_ws, size_t ws_size,
                              hipStream_t stream) {
    const float* sup = (const float*)d_in[0];   // [64, 8, 576]
    const float* qry = (const float*)d_in[1];   // [2048, 8, 576]
    float* out = (float*)d_out;                 // [2048, 64]

    // ws: tb bf16[132*128*576] (19.5 MB) | psum f32[132*18*128] (1.2 MB)
    unsigned short* tb = (unsigned short*)d_ws;
    float* psum = (float*)(tb + (size_t)NT * TILE_ELEMS);

    prep_kernel<<<dim3(NSLAB, NT), dim3(256), 0, stream>>>(sup, qry, tb, psum);
    fused_kernel<<<dim3(512), dim3(256), 0, stream>>>(tb, psum, out);
}